// Round 14
// baseline (473.669 us; speedup 1.0000x reference)
//
#include <hip/hip_runtime.h>
#include <cstdint>
#include <cstddef>

#define BATCH 8
#define SEQ   256
#define DIM   768
#define NSPAN 2020
#define HID   1024
#define NZ    64

typedef unsigned short u16;
typedef unsigned int   u32;
typedef unsigned long long u64;

typedef __bf16 bf16x8 __attribute__((ext_vector_type(8)));
typedef float  f32x4  __attribute__((ext_vector_type(4)));

__device__ __forceinline__ u16 f2bf(float f) {
    union { float f; u32 u; } x; x.f = f;
    u32 r = x.u + 0x7fffu + ((x.u >> 16) & 1u);
    return (u16)(r >> 16);
}
__device__ __forceinline__ float bf2f(u16 b) {
    union { u32 u; float f; } x; x.u = ((u32)b) << 16;
    return x.f;
}
// split v = hi + lo (both bf16); residual v-hi is exact in fp32
__device__ __forceinline__ void splitbf(float v, u16& h, u16& l) {
    h = f2bf(v);
    l = f2bf(v - bf2f(h));
}

// async global->LDS, 16B per lane; LDS dest = wave-uniform base + lane*16;
// global src may be per-lane (row gather OK) [m97/m104]
__device__ __forceinline__ void gld_lds16(const void* g, void* l) {
    __builtin_amdgcn_global_load_lds(
        (const __attribute__((address_space(1))) unsigned int*)g,
        (__attribute__((address_space(3))) unsigned int*)l, 16, 0, 0);
}

// span s -> (start, end, width); spans enumerated width-major: w=1..8, starts 0..L-w
__device__ __forceinline__ void span_decode(int s, int& start, int& end, int& w) {
    int off = 0;
#pragma unroll
    for (int wi = 1; wi <= 8; ++wi) {
        int cnt = SEQ - wi + 1;
        if (s < off + cnt) { w = wi; start = s - off; end = start + wi; return; }
        off += cnt;
    }
    w = 8; start = 0; end = 8;
}

// searchsorted(BUCKET_BINS, d, 'right') - 1
__device__ __forceinline__ int dbucket(int d) {
    int b = 0;
    b += (d >= 1);  b += (d >= 2);  b += (d >= 3);  b += (d >= 4);
    b += (d >= 5);  b += (d >= 7);  b += (d >= 8);  b += (d >= 15);
    b += (d >= 16); b += (d >= 31); b += (d >= 32); b += (d >= 63);
    b += (d >= 64);
    return b;
}

// XCD-aware deswizzle: (linear id) % 8 == by % 8 -> all column-blocks of one
// A-row-tile land on the SAME XCD (id%8 round-robin). sft = log2(nbx).
__device__ __forceinline__ void xcd_map(int L, int sft, int& bx, int& by) {
    int grp = L >> (3 + sft);
    int rem = L & ((1 << (3 + sft)) - 1);
    bx = rem >> 3;
    by = (grp << 3) | (rem & 7);
}

// ---------------------------------------------------------------------------
// k_prep (fused): x hi/lo split | bucket tables | all weight transposes.
// ---------------------------------------------------------------------------
__global__ __launch_bounds__(256) void k_prep(
    const float* __restrict__ x,  u16* __restrict__ xh,   u16* __restrict__ xl,
    const float* __restrict__ wemb, const float* __restrict__ demb,
    const float* __restrict__ bs1, const float* __restrict__ bp1,
    float* __restrict__ wtabS, float* __restrict__ wtabPt,
    float* __restrict__ wtabPo, float* __restrict__ dtab,
    const float* __restrict__ Ws1, u16* __restrict__ W1Th, u16* __restrict__ W1Tl,
    const float* __restrict__ Ws2, u16* __restrict__ W2Th, u16* __restrict__ W2Tl,
    const float* __restrict__ Wp2, u16* __restrict__ Wp2T,
    const float* __restrict__ Wp1, u16* __restrict__ Wp1T4)
{
    __shared__ float tile[32][33];
    const int bid = blockIdx.x, tid = threadIdx.x;
    if (bid < 6144) {
        int i = bid * 256 + tid;         // over 2048*768
        u16 h, l; splitbf(x[i], h, l);
        xh[i] = h; xl[i] = l;
        return;
    }
    if (bid < 6296) {
        int t = bid - 6144;              // 0..151
        int row = t >> 2;                // 0..37
        int h = (t & 3) * 256 + tid;     // 0..1023
        const int wb[8] = {1,2,3,4,5,5,6,7};
        if (row < 8) {
            int bk = wb[row];
            float acc = bs1[h];
            for (int j = 0; j < 25; ++j) acc = fmaf(wemb[bk*25+j], Ws1[(size_t)(1536+j)*HID + h], acc);
            wtabS[row*HID + h] = acc;
        } else if (row < 16) {
            int bk = wb[row-8];
            float acc = 0.f;
            for (int j = 0; j < 25; ++j) acc = fmaf(wemb[bk*25+j], Wp1[(size_t)(1536+j)*HID + h], acc);
            wtabPt[(row-8)*HID + h] = acc;
        } else if (row < 24) {
            int bk = wb[row-16];
            float acc = 0.f;
            for (int j = 0; j < 25; ++j) acc = fmaf(wemb[bk*25+j], Wp1[(size_t)(3097+j)*HID + h], acc);
            wtabPo[(row-16)*HID + h] = acc;
        } else {
            int tt = row - 24;           // 0..13
            float acc = bp1[h];
            for (int j = 0; j < 25; ++j) acc = fmaf(demb[tt*25+j], Wp1[(size_t)(3122+j)*HID + h], acc);
            dtab[tt*HID + h] = acc;
        }
        return;
    }
    // transpose jobs
    const int tb = bid - 6296;           // 0..6655
    const int tr = tid >> 3;             // 0..31
    const int tc4 = (tid & 7) * 4;       // 0,4,..,28
    int job, tk, tn, blk = 0;
    if (tb < 1536)      { job = 0; tk = tb % 24; tn = tb / 24; }
    else if (tb < 2560) { job = 1; int t = tb - 1536; tk = t & 31; tn = t >> 5; }
    else if (tb < 3584) { job = 2; int t = tb - 2560; tk = t & 31; tn = t >> 5; }
    else                { job = 3; int t = tb - 3584; blk = t / 768; int r = t - blk * 768; tk = r % 24; tn = r / 24; }
    const int k0 = tk * 32, n0 = tn * 32;

    int k = k0 + tr;
    float4 v;
    if (job == 0) {
        const float* s = (n0 < 1024) ? (Ws1 + (size_t)k * HID + n0)
                                     : (Ws1 + (size_t)(768 + k) * HID + (n0 - 1024));
        v = *(const float4*)(s + tc4);
    } else if (job == 1) {
        v = *(const float4*)(Ws2 + (size_t)k * HID + n0 + tc4);
    } else if (job == 2) {
        v = *(const float4*)(Wp2 + (size_t)k * HID + n0 + tc4);
    } else {
        const int roff[4] = {0, 768, 1561, 2329};   // (T,p0),(T,p1),(O,p0),(O,p1)
        v = *(const float4*)(Wp1 + (size_t)(roff[blk] + k) * HID + n0 + tc4);
    }
    tile[tr][tc4+0] = v.x; tile[tr][tc4+1] = v.y;
    tile[tr][tc4+2] = v.z; tile[tr][tc4+3] = v.w;
    __syncthreads();

    int nn = n0 + tr;
    float w0 = tile[tc4+0][tr], w1 = tile[tc4+1][tr];
    float w2 = tile[tc4+2][tr], w3 = tile[tc4+3][tr];
    if (job == 0) {
        size_t d = (size_t)nn * 768 + k0 + tc4;
        u16 h0,l0,h1,l1,h2,l2,h3,l3;
        splitbf(w0,h0,l0); splitbf(w1,h1,l1); splitbf(w2,h2,l2); splitbf(w3,h3,l3);
        *(uint2*)(W1Th + d) = make_uint2((u32)h0 | ((u32)h1 << 16), (u32)h2 | ((u32)h3 << 16));
        *(uint2*)(W1Tl + d) = make_uint2((u32)l0 | ((u32)l1 << 16), (u32)l2 | ((u32)l3 << 16));
    } else if (job == 1) {
        size_t d = (size_t)nn * 1024 + k0 + tc4;
        u16 h0,l0,h1,l1,h2,l2,h3,l3;
        splitbf(w0,h0,l0); splitbf(w1,h1,l1); splitbf(w2,h2,l2); splitbf(w3,h3,l3);
        *(uint2*)(W2Th + d) = make_uint2((u32)h0 | ((u32)h1 << 16), (u32)h2 | ((u32)h3 << 16));
        *(uint2*)(W2Tl + d) = make_uint2((u32)l0 | ((u32)l1 << 16), (u32)l2 | ((u32)l3 << 16));
    } else if (job == 2) {
        size_t d = (size_t)nn * 1024 + k0 + tc4;
        *(uint2*)(Wp2T + d) = make_uint2((u32)f2bf(w0) | ((u32)f2bf(w1) << 16),
                                         (u32)f2bf(w2) | ((u32)f2bf(w3) << 16));
    } else {
        size_t d = (size_t)blk * 786432 + (size_t)nn * 768 + k0 + tc4;
        *(uint2*)(Wp1T4 + d) = make_uint2((u32)f2bf(w0) | ((u32)f2bf(w1) << 16),
                                          (u32)f2bf(w2) | ((u32)f2bf(w3) << 16));
    }
}

// ---------------------------------------------------------------------------
// Error-compensated split-bf16 MFMA GEMM: C = AhBh + AlBh + AhBl  (XALL path)
// 128x128 tile, BK=32, global_load_lds staging, XCD-aware grid.
// ---------------------------------------------------------------------------
__global__ __launch_bounds__(256) void k_gemm3bf(
    const u16* __restrict__ Ah, const u16* __restrict__ Al, int lda,
    const u16* __restrict__ BTh, const u16* __restrict__ BTl, int ldb,
    float* __restrict__ C, int ldc,
    int M, int K, int nby, int sft)
{
    int bx, by;
    xcd_map(blockIdx.x, sft, bx, by);
    if (by >= nby) return;
    __shared__ __align__(16) u16 sm[4 * 128 * 32];     // 32 KiB
    u16* sAh = sm;
    u16* sAl = sm + 4096;
    u16* sBh = sm + 8192;
    u16* sBl = sm + 12288;
    const int tid = threadIdx.x;
    const int bm = by * 128, bn = bx * 128;
    const int wave = tid >> 6, lane = tid & 63;
    const int wr = wave >> 1, wc = wave & 1;
    const int q = lane >> 4, tl = lane & 15;

    f32x4 zero = {0.f, 0.f, 0.f, 0.f};
    f32x4 acc[4][4];
#pragma unroll
    for (int i = 0; i < 4; ++i)
#pragma unroll
        for (int j = 0; j < 4; ++j) acc[i][j] = zero;

    const int srow = lane >> 2;
    const int scol = (lane & 3) * 8;
    int ra0 = bm + wave * 32 + srow;      if (ra0 >= M) ra0 = M - 1;
    int ra1 = bm + wave * 32 + 16 + srow; if (ra1 >= M) ra1 = M - 1;
    const int rb0 = bn + wave * 32 + srow;
    const int rb1 = bn + wave * 32 + 16 + srow;
    u16* dA0 = sAh + wave * 1024;  u16* dA1 = dA0 + 512;
    u16* dL0 = sAl + wave * 1024;  u16* dL1 = dL0 + 512;
    u16* dB0 = sBh + wave * 1024;  u16* dB1 = dB0 + 512;
    u16* dC0 = sBl + wave * 1024;  u16* dC1 = dC0 + 512;
    const u16* gA0 = Ah  + (size_t)ra0 * lda + scol;
    const u16* gA1 = Ah  + (size_t)ra1 * lda + scol;
    const u16* gL0 = Al  + (size_t)ra0 * lda + scol;
    const u16* gL1 = Al  + (size_t)ra1 * lda + scol;
    const u16* gB0 = BTh + (size_t)rb0 * ldb + scol;
    const u16* gB1 = BTh + (size_t)rb1 * ldb + scol;
    const u16* gC0 = BTl + (size_t)rb0 * ldb + scol;
    const u16* gC1 = BTl + (size_t)rb1 * ldb + scol;

    for (int k0 = 0; k0 < K; k0 += 32) {
        gld_lds16(gA0 + k0, dA0);
        gld_lds16(gA1 + k0, dA1);
        gld_lds16(gL0 + k0, dL0);
        gld_lds16(gL1 + k0, dL1);
        gld_lds16(gB0 + k0, dB0);
        gld_lds16(gB1 + k0, dB1);
        gld_lds16(gC0 + k0, dC0);
        gld_lds16(gC1 + k0, dC1);
        __syncthreads();
        bf16x8 ah[4], al[4], bh[4], bl[4];
#pragma unroll
        for (int t = 0; t < 4; ++t) {
            int arow = (wr*64 + t*16 + tl) * 32 + q*8;
            int brow = (wc*64 + t*16 + tl) * 32 + q*8;
            ah[t] = *(const bf16x8*)(&sAh[arow]);
            al[t] = *(const bf16x8*)(&sAl[arow]);
            bh[t] = *(const bf16x8*)(&sBh[brow]);
            bl[t] = *(const bf16x8*)(&sBl[brow]);
        }
#pragma unroll
        for (int ti = 0; ti < 4; ++ti)
#pragma unroll
            for (int tj = 0; tj < 4; ++tj) {
                acc[ti][tj] = __builtin_amdgcn_mfma_f32_16x16x32_bf16(ah[ti], bh[tj], acc[ti][tj], 0, 0, 0);
                acc[ti][tj] = __builtin_amdgcn_mfma_f32_16x16x32_bf16(al[ti], bh[tj], acc[ti][tj], 0, 0, 0);
                acc[ti][tj] = __builtin_amdgcn_mfma_f32_16x16x32_bf16(ah[ti], bl[tj], acc[ti][tj], 0, 0, 0);
            }
        __syncthreads();
    }
    // C/D layout: col = lane&15, row = (lane>>4)*4 + reg  [measured m89/m91]
#pragma unroll
    for (int ti = 0; ti < 4; ++ti) {
#pragma unroll
        for (int tj = 0; tj < 4; ++tj) {
            int gcol = bn + wc*64 + tj*16 + tl;
#pragma unroll
            for (int r = 0; r < 4; ++r) {
                int grow = bm + wr*64 + ti*16 + q*4 + r;
                if (grow >= M) continue;
                C[(size_t)grow * ldc + gcol] = acc[ti][tj][r];
            }
        }
    }
}

// ---------------------------------------------------------------------------
// Span layer-2 GEMM with FUSED layer-3 projection epilogue (deterministic).
// ---------------------------------------------------------------------------
__global__ __launch_bounds__(256) void k_span_l2(
    const u16* __restrict__ Ah, const u16* __restrict__ Al,
    const u16* __restrict__ BTh, const u16* __restrict__ BTl,
    const float* __restrict__ bs2, const float* __restrict__ Ws3,
    float* __restrict__ part, int M)
{
    int bx, by;
    xcd_map(blockIdx.x, 3, bx, by);
    if (by >= 127) return;
    __shared__ __align__(16) u16 sm[4 * 128 * 32];
    u16* sAh = sm;
    u16* sAl = sm + 4096;
    u16* sBh = sm + 8192;
    u16* sBl = sm + 12288;
    const int tid = threadIdx.x;
    const int bm = by * 128, bn = bx * 128;
    const int wave = tid >> 6, lane = tid & 63;
    const int wr = wave >> 1, wc = wave & 1;
    const int q = lane >> 4, tl = lane & 15;

    f32x4 zero = {0.f, 0.f, 0.f, 0.f};
    f32x4 acc[4][4];
#pragma unroll
    for (int i = 0; i < 4; ++i)
#pragma unroll
        for (int j = 0; j < 4; ++j) acc[i][j] = zero;

    const int srow = lane >> 2;
    const int scol = (lane & 3) * 8;
    int ra0 = bm + wave * 32 + srow;      if (ra0 >= M) ra0 = M - 1;
    int ra1 = bm + wave * 32 + 16 + srow; if (ra1 >= M) ra1 = M - 1;
    const int rb0 = bn + wave * 32 + srow;
    const int rb1 = bn + wave * 32 + 16 + srow;
    u16* dA0 = sAh + wave * 1024;  u16* dA1 = dA0 + 512;
    u16* dL0 = sAl + wave * 1024;  u16* dL1 = dL0 + 512;
    u16* dB0 = sBh + wave * 1024;  u16* dB1 = dB0 + 512;
    u16* dC0 = sBl + wave * 1024;  u16* dC1 = dC0 + 512;
    const u16* gA0 = Ah  + (size_t)ra0 * HID + scol;
    const u16* gA1 = Ah  + (size_t)ra1 * HID + scol;
    const u16* gL0 = Al  + (size_t)ra0 * HID + scol;
    const u16* gL1 = Al  + (size_t)ra1 * HID + scol;
    const u16* gB0 = BTh + (size_t)rb0 * HID + scol;
    const u16* gB1 = BTh + (size_t)rb1 * HID + scol;
    const u16* gC0 = BTl + (size_t)rb0 * HID + scol;
    const u16* gC1 = BTl + (size_t)rb1 * HID + scol;

    for (int k0 = 0; k0 < HID; k0 += 32) {
        gld_lds16(gA0 + k0, dA0);
        gld_lds16(gA1 + k0, dA1);
        gld_lds16(gL0 + k0, dL0);
        gld_lds16(gL1 + k0, dL1);
        gld_lds16(gB0 + k0, dB0);
        gld_lds16(gB1 + k0, dB1);
        gld_lds16(gC0 + k0, dC0);
        gld_lds16(gC1 + k0, dC1);
        __syncthreads();
        bf16x8 ah[4], al[4], bh[4], bl[4];
#pragma unroll
        for (int t = 0; t < 4; ++t) {
            int arow = (wr*64 + t*16 + tl) * 32 + q*8;
            int brow = (wc*64 + t*16 + tl) * 32 + q*8;
            ah[t] = *(const bf16x8*)(&sAh[arow]);
            al[t] = *(const bf16x8*)(&sAl[arow]);
            bh[t] = *(const bf16x8*)(&sBh[brow]);
            bl[t] = *(const bf16x8*)(&sBl[brow]);
        }
#pragma unroll
        for (int ti = 0; ti < 4; ++ti)
#pragma unroll
            for (int tj = 0; tj < 4; ++tj) {
                acc[ti][tj] = __builtin_amdgcn_mfma_f32_16x16x32_bf16(ah[ti], bh[tj], acc[ti][tj], 0, 0, 0);
                acc[ti][tj] = __builtin_amdgcn_mfma_f32_16x16x32_bf16(al[ti], bh[tj], acc[ti][tj], 0, 0, 0);
                acc[ti][tj] = __builtin_amdgcn_mfma_f32_16x16x32_bf16(ah[ti], bl[tj], acc[ti][tj], 0, 0, 0);
            }
        __syncthreads();
    }
    // fused L3: per row, partial dot over this wave's 64-col window
    const int slot = bx * 2 + wc;   // 0..15
#pragma unroll
    for (int ti = 0; ti < 4; ++ti) {
#pragma unroll
        for (int r = 0; r < 4; ++r) {
            int grow = bm + wr*64 + ti*16 + q*4 + r;
            float l0 = 0.f, l1 = 0.f, l2 = 0.f;
#pragma unroll
            for (int tj = 0; tj < 4; ++tj) {
                int gcol = bn + wc*64 + tj*16 + tl;
                float v = fmaxf(acc[ti][tj][r] + bs2[gcol], 0.f);
                const float* w3 = Ws3 + gcol * 3;
                l0 = fmaf(v, w3[0], l0);
                l1 = fmaf(v, w3[1], l1);
                l2 = fmaf(v, w3[2], l2);
            }
#pragma unroll
            for (int off = 8; off > 0; off >>= 1) {
                l0 += __shfl_down(l0, off, 16);
                l1 += __shfl_down(l1, off, 16);
                l2 += __shfl_down(l2, off, 16);
            }
            if (tl == 0 && grow < M) {
                float* dst = part + ((size_t)grow * 16 + slot) * 3;
                dst[0] = l0; dst[1] = l1; dst[2] = l2;
            }
        }
    }
}

// ---------------------------------------------------------------------------
// Gathered pair layer-1, split-K over p: TO2[p][r] = xh[toks[r + p*1024]]@B(p)
// ---------------------------------------------------------------------------
__global__ __launch_bounds__(256) void k_pairL1(
    const u16* __restrict__ xh, const u16* __restrict__ Wp1T4,
    float* __restrict__ TO2, const int* __restrict__ toks)
{
    __shared__ __align__(16) u16 sm[2 * 64 * 32];   // A 4KB | B 4KB
    u16* sA = sm;
    u16* sB = sm + 2048;
    const int tid = threadIdx.x;
    const int bid = blockIdx.x;
    const int p = bid >> 8;                  // 0/1
    const int bx = bid & 15, by = (bid >> 4) & 15;
    const int bm = by * 64, bn = bx * 64;
    const int wave = tid >> 6, lane = tid & 63;
    const int wr = wave >> 1, wc = wave & 1;
    const int q = lane >> 4, tl = lane & 15;
    const bool isO = bm >= 512;

    f32x4 zero = {0.f, 0.f, 0.f, 0.f};
    f32x4 acc[2][2];
#pragma unroll
    for (int i = 0; i < 2; ++i)
#pragma unroll
        for (int j = 0; j < 2; ++j) acc[i][j] = zero;

    const int srow = tid >> 2;
    const int scol = (tid & 3) * 8;
    u16* dA = sA + wave * 512;
    u16* dB = sB + wave * 512;

    int arow = toks[bm + srow + p * 1024];    // per-lane row gather
    const u16* gA = xh + (size_t)arow * DIM + scol;
    const u16* gB = Wp1T4 + ((size_t)((isO ? 2 : 0) + p) * 1024 + bn + srow) * DIM + scol;
    for (int k0 = 0; k0 < DIM; k0 += 32) {
        gld_lds16(gA + k0, dA);
        gld_lds16(gB + k0, dB);
        __syncthreads();
        bf16x8 af[2], bf[2];
#pragma unroll
        for (int t = 0; t < 2; ++t) {
            af[t] = *(const bf16x8*)(&sA[(wr*32 + t*16 + tl) * 32 + q*8]);
            bf[t] = *(const bf16x8*)(&sB[(wc*32 + t*16 + tl) * 32 + q*8]);
        }
#pragma unroll
        for (int ti = 0; ti < 2; ++ti)
#pragma unroll
            for (int tj = 0; tj < 2; ++tj)
                acc[ti][tj] = __builtin_amdgcn_mfma_f32_16x16x32_bf16(af[ti], bf[tj], acc[ti][tj], 0, 0, 0);
        __syncthreads();
    }
    float* dstb = TO2 + (size_t)p * 1024 * HID;
#pragma unroll
    for (int ti = 0; ti < 2; ++ti) {
#pragma unroll
        for (int tj = 0; tj < 2; ++tj) {
            int gcol = bn + wc*32 + tj*16 + tl;
#pragma unroll
            for (int r = 0; r < 4; ++r) {
                int grow = bm + wr*32 + ti*16 + q*4 + r;
                dstb[(size_t)grow * HID + gcol] = acc[ti][tj][r];
            }
        }
    }
}

// h1s = relu(XALL[b,start,0:1024] + XALL[b,end-1,1024:2048] + wtabS[w-1]) -> split bf16
__global__ __launch_bounds__(256) void k_build_h1s(
    const float* __restrict__ XALL, const float* __restrict__ wtabS,
    u16* __restrict__ h1h, u16* __restrict__ h1l)
{
    int r = blockIdx.x;                 // 0..16159
    int b = r / NSPAN, s = r - b * NSPAN;
    int st, en, w; span_decode(s, st, en, w);
    const float4* xs = (const float4*)(XALL + (size_t)(b*SEQ + st) * 2048);
    const float4* xe = (const float4*)(XALL + (size_t)(b*SEQ + en - 1) * 2048 + 1024);
    const float4* wt = (const float4*)(wtabS + (size_t)(w-1) * HID);
    int t = threadIdx.x;
    float4 a = xs[t], bz = xe[t], c = wt[t];
    float v0 = fmaxf(a.x + bz.x + c.x, 0.f);
    float v1 = fmaxf(a.y + bz.y + c.y, 0.f);
    float v2 = fmaxf(a.z + bz.z + c.z, 0.f);
    float v3 = fmaxf(a.w + bz.w + c.w, 0.f);
    u16 h0,l0,h1,l1,h2,l2,h3,l3;
    splitbf(v0,h0,l0); splitbf(v1,h1,l1); splitbf(v2,h2,l2); splitbf(v3,h3,l3);
    size_t base = (size_t)r * HID + t * 4;
    *(uint2*)(h1h + base) = make_uint2((u32)h0 | ((u32)h1 << 16), (u32)h2 | ((u32)h3 << 16));
    *(uint2*)(h1l + base) = make_uint2((u32)l0 | ((u32)l1 << 16), (u32)l2 | ((u32)l3 << 16));
}

// ---------------------------------------------------------------------------
// k_topk (fused with span reduce+softmax): reduces partS (fixed order), writes
// out[], packs keys, bitonic-sorts 2048 u64 keys, emits top-64 + token maps.
// ---------------------------------------------------------------------------
__global__ __launch_bounds__(256) void k_topk(
    const float* __restrict__ partS, const float* __restrict__ bs3,
    float* __restrict__ out, int* __restrict__ t_idx, int* __restrict__ o_idx,
    int* __restrict__ toks)
{
    int b = blockIdx.x >> 1;
    int head = 1 + (blockIdx.x & 1);
    int* outp = (head == 1 ? t_idx : o_idx) + b * NZ;
    __shared__ u64 keys[2048];
    int tid = threadIdx.x;
#pragma unroll
    for (int ii = 0; ii < 8; ++ii) {
        int s = tid + ii * 256;          // 0..2047
        u32 fb = 0;
        if (s < NSPAN) {
            const float* p = partS + (size_t)(b * NSPAN + s) * 48;
            float s0 = bs3[0], s1 = bs3[1], s2 = bs3[2];
#pragma unroll
            for (int t = 0; t < 16; ++t) {
                s0 += p[t*3]; s1 += p[t*3+1]; s2 += p[t*3+2];
            }
            float m = fmaxf(s0, fmaxf(s1, s2));
            float e0 = expf(s0 - m), e1 = expf(s1 - m), e2 = expf(s2 - m);
            float inv = 1.f / (e0 + e1 + e2);
            float p0 = e0 * inv, p1 = e1 * inv, p2 = e2 * inv;
            float* o = out + (size_t)(b * NSPAN + s) * 3;
            o[0] = p0; o[1] = p1; o[2] = p2;
            union { float f; u32 u; } x;
            x.f = (head == 1) ? p1 : p2;
            fb = x.u;
        }
        keys[s] = ((u64)fb << 32) | (u64)(0xFFFFFFFFu - (u32)s);
    }
    __syncthreads();
    for (int k = 2; k <= 2048; k <<= 1) {
        for (int j = k >> 1; j > 0; j >>= 1) {
#pragma unroll
            for (int ii = 0; ii < 8; ++ii) {
                int i = tid + ii * 256;
                int ixj = i ^ j;
                if (ixj > i) {
                    u64 a = keys[i], c = keys[ixj];
                    bool desc = (i & k) == 0;
                    bool wrong = desc ? (a < c) : (a > c);
                    if (wrong) { keys[i] = c; keys[ixj] = a; }
                }
            }
            __syncthreads();
        }
    }
    if (tid < NZ) {
        u64 key = keys[tid];
        int fi = (int)(0xFFFFFFFFu - (u32)(key & 0xFFFFFFFFu));
        if (fi < 0 || fi >= NSPAN) fi = 0;   // paranoia
        outp[tid] = fi;
        int st, en, w; span_decode(fi, st, en, w);
        int base = (head == 1 ? 0 : 512) + b * NZ + tid;
        toks[base] = b * SEQ + st;
        toks[1024 + base] = b * SEQ + en - 1;
    }
}

// h1_pair[row] = relu(TO2[0]+TO2[1] (T) + (O) + wtabPt + wtabPo + dtab) -> bf16
__global__ __launch_bounds__(256) void k_build_h1p(
    const float* __restrict__ TO2, const int* __restrict__ t_idx, const int* __restrict__ o_idx,
    const float* __restrict__ wtabPt, const float* __restrict__ wtabPo,
    const float* __restrict__ dtab, u16* __restrict__ h1p)
{
    int row = blockIdx.x;               // b*4096 + i*64 + j
    int b = row >> 12, i = (row >> 6) & 63, j = row & 63;
    int ts = t_idx[b*64 + i], os = o_idx[b*64 + j];
    int ta, tb, wt, oc, od, wo;
    span_decode(ts, ta, tb, wt);
    span_decode(os, oc, od, wo);
    int d1 = tb - oc; d1 = d1 < 0 ? -d1 : d1;
    int d2 = ta - od; d2 = d2 < 0 ? -d2 : d2;
    int dist = d1 < d2 ? d1 : d2;
    int db = dbucket(dist);
    const size_t PS = (size_t)1024 * HID;
    const float4* T0 = (const float4*)(TO2 + (size_t)(b*64 + i) * HID);
    const float4* T1 = (const float4*)(TO2 + PS + (size_t)(b*64 + i) * HID);
    const float4* O0 = (const float4*)(TO2 + (size_t)(512 + b*64 + j) * HID);
    const float4* O1 = (const float4*)(TO2 + PS + (size_t)(512 + b*64 + j) * HID);
    const float4* P4 = (const float4*)(wtabPt + (size_t)(wt-1) * HID);
    const float4* Q4 = (const float4*)(wtabPo + (size_t)(wo-1) * HID);
    const float4* D4 = (const float4*)(dtab + (size_t)db * HID);
    int t = threadIdx.x;
    float4 a0 = T0[t], a1 = T1[t], c0 = O0[t], c1 = O1[t];
    float4 p = P4[t], q = Q4[t], d = D4[t];
    float vx = fmaxf(a0.x + a1.x + c0.x + c1.x + p.x + q.x + d.x, 0.f);
    float vy = fmaxf(a0.y + a1.y + c0.y + c1.y + p.y + q.y + d.y, 0.f);
    float vz = fmaxf(a0.z + a1.z + c0.z + c1.z + p.z + q.z + d.z, 0.f);
    float vw = fmaxf(a0.w + a1.w + c0.w + c1.w + p.w + q.w + d.w, 0.f);
    u32 p0 = (u32)f2bf(vx) | ((u32)f2bf(vy) << 16);
    u32 p1 = (u32)f2bf(vz) | ((u32)f2bf(vw) << 16);
    *(uint2*)(h1p + (size_t)row * HID + t * 4) = make_uint2(p0, p1);
}

// ---------------------------------------------------------------------------
// pair layer2 with FUSED layer-3 epilogue. BK=64 (two 32-wide sub-tiles per
// iteration staged into separate [128][32] arrays -> same bank behavior as
// BK=32 but 32 MFMA per barrier pair, half the barrier drains).
// ---------------------------------------------------------------------------
__global__ __launch_bounds__(256) void k_pair_l2(
    const u16* __restrict__ Abf, const u16* __restrict__ BT,
    const float* __restrict__ bp2, const float* __restrict__ Wp3,
    float* __restrict__ part)
{
    int bx, by;
    xcd_map(blockIdx.x, 3, bx, by);
    __shared__ __align__(16) u16 sm[4 * 128 * 32];     // 32 KiB
    u16* As0 = sm;            // k0..k0+31
    u16* As1 = sm + 4096;     // k0+32..k0+63
    u16* Bs0 = sm + 8192;
    u16* Bs1 = sm + 12288;
    const int tid = threadIdx.x;
    const int bm = by * 128, bn = bx * 128;
    const int wave = tid >> 6, lane = tid & 63;
    const int wr = wave >> 1, wc = wave & 1;
    const int q = lane >> 4, tl = lane & 15;

    f32x4 zero = {0.f, 0.f, 0.f, 0.f};
    f32x4 acc[4][4];
#pragma unroll
    for (int i = 0; i < 4; ++i)
#pragma unroll
        for (int j = 0; j < 4; ++j) acc[i][j] = zero;

    const int srow = lane >> 2;
    const int scol = (lane & 3) * 8;
    const u16* gA0 = Abf + (size_t)(bm + wave*32 + srow) * 1024 + scol;
    const u16* gA1 = Abf + (size_t)(bm + wave*32 + 16 + srow) * 1024 + scol;
    const u16* gB0 = BT  + (size_t)(bn + wave*32 + srow) * 1024 + scol;
    const u16* gB1 = BT  + (size_t)(bn + wave*32 + 16 + srow) * 1024 + scol;
    u16* dA00 = As0 + wave * 1024;  u16* dA01 = dA00 + 512;
    u16* dA10 = As1 + wave * 1024;  u16* dA11 = dA10 + 512;
    u16* dB00 = Bs0 + wave * 1024;  u16* dB01 = dB00 + 512;
    u16* dB10 = Bs1 + wave * 1024;  u16* dB11 = dB10 + 512;

    for (int k0 = 0; k0 < 1024; k0 += 64) {
        gld_lds16(gA0 + k0, dA00);
        gld_lds16(gA1 + k0, dA01);
        gld_lds16(gA0 + k0 + 32, dA10);
        gld_lds16(gA1 + k0 + 32, dA11);
        gld_lds16(gB0 + k0, dB00);
        gld_lds16(gB1 + k0, dB01);
        gld_lds16(gB0 + k0 + 32, dB10);
        gld_lds16(gB1 + k0 + 32, dB11);
        __syncthreads();
        bf16x8 a0[4], a1[4], b0[4], b1[4];
#pragma unroll
        for (int t = 0; t < 4; ++t) {
            int arow = (wr*64 + t*16 + tl) * 32 + q*8;
            int brow = (wc*64 + t*16 + tl) * 32 + q*8;
            a0[t] = *(const bf16x8*)(&As0[arow]);
            a1[t] = *(const bf16x8*)(&As1[arow]);
            b0[t] = *(const bf16x8*)(&Bs0[brow]);
            b1[t] = *(const bf16x8*)(&Bs1[brow]);
        }
#pragma unroll
        for (int ti = 0; ti < 4; ++ti)
#pragma unroll
            for (int tj = 0; tj < 4; ++tj) {
                acc[ti][tj] = __builtin_amdgcn_mfma_f32_16x16x32_bf16(a0[ti], b0[tj], acc[ti][tj], 0, 0, 0);
                acc[ti][tj] = __builtin_amdgcn_mfma_f32_16x16x32_bf16(a1[ti], b1[tj], acc[ti][tj], 0, 0, 0);
            }
        __syncthreads();
    }
    // fused L3 projection
    const int slot = bx * 2 + wc;   // 0..15
#pragma unroll
    for (int ti = 0; ti < 4; ++ti) {
#pragma unroll
        for (int r = 0; r < 4; ++r) {
            int grow = bm + wr*64 + ti*16 + q*4 + r;
            float l0 = 0.f, l1 = 0.f, l2 = 0.f, l3 = 0.f;
#pragma unroll
            for (int tj = 0; tj < 4; ++tj) {
                int gcol = bn + wc*64 + tj*16 + tl;
                float v = fmaxf(acc[ti][tj][r] + bp2[gcol], 0.f);
                const float4 w = *(const float4*)(Wp3 + gcol * 4);
                l0 = fmaf(v, w.x, l0); l1 = fmaf(v, w.y, l1);
                l2 = fmaf(v, w.z, l2); l3 = fmaf(v, w.w, l3);
            }
#pragma unroll
            for (int off = 8; off > 0; off >>= 1) {
                l0 += __shfl_down(l0, off, 16);
                l1 += __shfl_down(l1, off, 16);
                l2 += __shfl_down(l2, off, 16);
                l3 += __shfl_down(l3, off, 16);
            }
            if (tl == 0) {
                float* dst = part + ((size_t)grow * 16 + slot) * 4;
                dst[0] = l0; dst[1] = l1; dst[2] = l2; dst[3] = l3;
            }
        }
    }
}

// reduce 16 slots (fixed order) + softmax -> out[48480 + r*4 + c]
__global__ __launch_bounds__(256) void k_pair_red(
    const float* __restrict__ part, const float* __restrict__ bp3,
    float* __restrict__ out)
{
    int r = blockIdx.x * 256 + threadIdx.x;   // 32768 = 128*256 exact
    const float4* p = (const float4*)(part + (size_t)r * 64);
    float s0 = bp3[0], s1 = bp3[1], s2 = bp3[2], s3 = bp3[3];
#pragma unroll
    for (int t = 0; t < 16; ++t) {
        float4 v = p[t];
        s0 += v.x; s1 += v.y; s2 += v.z; s3 += v.w;
    }
    float m = fmaxf(fmaxf(s0, s1), fmaxf(s2, s3));
    float e0 = expf(s0 - m), e1 = expf(s1 - m), e2 = expf(s2 - m), e3 = expf(s3 - m);
    float inv = 1.f / (e0 + e1 + e2 + e3);
    float* o = out + (size_t)r * 4;
    o[0] = e0 * inv; o[1] = e1 * inv; o[2] = e2 * inv; o[3] = e3 * inv;
}

extern "C" void kernel_launch(void* const* d_in, const int* in_sizes, int n_in,
                              void* d_out, int out_size, void* d_ws, size_t ws_size,
                              hipStream_t stream)
{
    const float* x    = (const float*)d_in[0];
    const float* wemb = (const float*)d_in[1];
    const float* demb = (const float*)d_in[2];
    const float* Ws1  = (const float*)d_in[3];
    const float* bs1  = (const float*)d_in[4];
    const float* Ws2  = (const float*)d_in[5];
    const float* bs2  = (const float*)d_in[6];
    const float* Ws3  = (const float*)d_in[7];
    const float* bs3  = (const float*)d_in[8];
    const float* Wp1  = (const float*)d_in[9];
    const float* bp1  = (const float*)d_in[10];
    const float* Wp2  = (const float*)d_in[11];
    const float* bp2  = (const float*)d_in[12];
    const float* Wp3  = (const float*)d_in[13];
    const float* bp3  = (const float*)d_in[14];
    float* out = (float*)d_out;
    char* ws = (char*)d_ws;

    // ---- workspace arena, lifetime-aliased (~162 MB) ----
    const size_t RSZ = (size_t)32768 * HID * 2;   // 64 MiB
    size_t off = 0;
    auto alloc = [&](size_t bytes) -> void* {
        void* p = ws + off;
        off += (bytes + 255) & ~(size_t)255;
        return p;
    };
    char* R1 = (char*)alloc(RSZ);
    char* R2 = (char*)alloc(RSZ);
    u16*   h1h  = (u16*)R1;                              // 33.1 MB
    u16*   h1l  = (u16*)(R1 + (size_t)16160 * HID * 2);  // 33.1 MB
    float* XALL = (float*)R2;                            // 16 MiB
    u16*   xl   = (u16*)(R2 + (16u << 20));              // 3 MB
    u16*   W1Th = (u16*)(R2 + (19u << 20));              // 3 MB
    u16*   W1Tl = (u16*)(R2 + (22u << 20));              // 3 MB
    u16*   h1p  = (u16*)R2;                              // 64 MiB (after the above dead)
    u16*   xh     = (u16*)alloc((size_t)2048 * DIM * 2);     // 3 MB PERSISTENT
    float* TO2    = (float*)alloc((size_t)2 * 1024 * HID * 4);   // 8 MB
    float* partS  = (float*)alloc((size_t)16160 * 16 * 3 * 4);   // 3.1 MB
    float* partP  = (float*)alloc((size_t)32768 * 16 * 4 * 4);   // 8.4 MB
    u16*   W2Th   = (u16*)alloc((size_t)1024 * 1024 * 2);
    u16*   W2Tl   = (u16*)alloc((size_t)1024 * 1024 * 2);
    u16*   Wp2T   = (u16*)alloc((size_t)1024 * 1024 * 2);
    u16*   Wp1T4  = (u16*)alloc((size_t)4 * 1024 * 768 * 2);
    float* wtabS  = (float*)alloc(8 * HID * 4);
    float* wtabPt = (float*)alloc(8 * HID * 4);
    float* wtabPo = (float*)alloc(8 * HID * 4);
    float* dtab   = (float*)alloc(14 * HID * 4);
    int*   t_idx  = (int*)alloc(BATCH * NZ * 4);
    int*   o_idx  = (int*)alloc(BATCH * NZ * 4);
    int*   toks   = (int*)alloc(2048 * 4);
    (void)ws_size; (void)in_sizes; (void)n_in; (void)out_size;

    // prep (fused): x split + tables + all weight transposes
    k_prep<<<12952, 256, 0, stream>>>(x, xh, xl, wemb, demb, bs1, bp1,
                                      wtabS, wtabPt, wtabPo, dtab,
                                      Ws1, W1Th, W1Tl, Ws2, W2Th, W2Tl,
                                      Wp2, Wp2T, Wp1, Wp1T4);

    // layer-1 factorization: XALL = x2d @ [Ws1_top | Ws1_mid] (3-pass split-bf16)
    k_gemm3bf<<<256, 256, 0, stream>>>(xh, xl, 768, W1Th, W1Tl, 768,
                                       XALL, 2048, 2048, 768, 16, 4);
    k_build_h1s<<<16160, 256, 0, stream>>>(XALL, wtabS, h1h, h1l);
    // span layer2 + FUSED layer3 partials (3-pass split-bf16, deterministic)
    k_span_l2<<<1024, 256, 0, stream>>>(h1h, h1l, W2Th, W2Tl, bs2, Ws3, partS, 16160);
    // fused reduce+softmax+topk+toks
    k_topk<<<16, 256, 0, stream>>>(partS, bs3, out, t_idx, o_idx, toks);
    // gathered pair layer-1: split-K bf16 MFMA
    k_pairL1<<<512, 256, 0, stream>>>(xh, Wp1T4, TO2, toks);
    k_build_h1p<<<32768, 256, 0, stream>>>(TO2, t_idx, o_idx, wtabPt, wtabPo, dtab, h1p);
    // pair layer2 + FUSED layer3 partials (BK=64: 2x MFMA per barrier)
    k_pair_l2<<<2048, 256, 0, stream>>>(h1p, Wp2T, bp2, Wp3, partP);
    k_pair_red<<<128, 256, 0, stream>>>(partP, bp3, out + 48480);
}

// Round 15
// 467.979 us; speedup vs baseline: 1.0122x; 1.0122x over previous
//
#include <hip/hip_runtime.h>
#include <cstdint>
#include <cstddef>

#define BATCH 8
#define SEQ   256
#define DIM   768
#define NSPAN 2020
#define HID   1024
#define NZ    64

typedef unsigned short u16;
typedef unsigned int   u32;
typedef unsigned long long u64;

typedef __bf16 bf16x8 __attribute__((ext_vector_type(8)));
typedef float  f32x4  __attribute__((ext_vector_type(4)));

__device__ __forceinline__ u16 f2bf(float f) {
    union { float f; u32 u; } x; x.f = f;
    u32 r = x.u + 0x7fffu + ((x.u >> 16) & 1u);
    return (u16)(r >> 16);
}
__device__ __forceinline__ float bf2f(u16 b) {
    union { u32 u; float f; } x; x.u = ((u32)b) << 16;
    return x.f;
}
// split v = hi + lo (both bf16); residual v-hi is exact in fp32
__device__ __forceinline__ void splitbf(float v, u16& h, u16& l) {
    h = f2bf(v);
    l = f2bf(v - bf2f(h));
}

// async global->LDS, 16B per lane; LDS dest = wave-uniform base + lane*16;
// global src may be per-lane (row gather OK) [m97/m104]
__device__ __forceinline__ void gld_lds16(const void* g, void* l) {
    __builtin_amdgcn_global_load_lds(
        (const __attribute__((address_space(1))) unsigned int*)g,
        (__attribute__((address_space(3))) unsigned int*)l, 16, 0, 0);
}

// span s -> (start, end, width); spans enumerated width-major: w=1..8, starts 0..L-w
__device__ __forceinline__ void span_decode(int s, int& start, int& end, int& w) {
    int off = 0;
#pragma unroll
    for (int wi = 1; wi <= 8; ++wi) {
        int cnt = SEQ - wi + 1;
        if (s < off + cnt) { w = wi; start = s - off; end = start + wi; return; }
        off += cnt;
    }
    w = 8; start = 0; end = 8;
}

// searchsorted(BUCKET_BINS, d, 'right') - 1
__device__ __forceinline__ int dbucket(int d) {
    int b = 0;
    b += (d >= 1);  b += (d >= 2);  b += (d >= 3);  b += (d >= 4);
    b += (d >= 5);  b += (d >= 7);  b += (d >= 8);  b += (d >= 15);
    b += (d >= 16); b += (d >= 31); b += (d >= 32); b += (d >= 63);
    b += (d >= 64);
    return b;
}

// XCD-aware deswizzle: (linear id) % 8 == by % 8 -> all column-blocks of one
// A-row-tile land on the SAME XCD (id%8 round-robin). sft = log2(nbx).
__device__ __forceinline__ void xcd_map(int L, int sft, int& bx, int& by) {
    int grp = L >> (3 + sft);
    int rem = L & ((1 << (3 + sft)) - 1);
    bx = rem >> 3;
    by = (grp << 3) | (rem & 7);
}

// ---------------------------------------------------------------------------
// k_prep (fused): x hi/lo split | bucket tables | all weight transposes.
// ---------------------------------------------------------------------------
__global__ __launch_bounds__(256) void k_prep(
    const float* __restrict__ x,  u16* __restrict__ xh,   u16* __restrict__ xl,
    const float* __restrict__ wemb, const float* __restrict__ demb,
    const float* __restrict__ bs1, const float* __restrict__ bp1,
    float* __restrict__ wtabS, float* __restrict__ wtabPt,
    float* __restrict__ wtabPo, float* __restrict__ dtab,
    const float* __restrict__ Ws1, u16* __restrict__ W1Th, u16* __restrict__ W1Tl,
    const float* __restrict__ Ws2, u16* __restrict__ W2Th, u16* __restrict__ W2Tl,
    const float* __restrict__ Wp2, u16* __restrict__ Wp2T,
    const float* __restrict__ Wp1, u16* __restrict__ Wp1T4)
{
    __shared__ float tile[32][33];
    const int bid = blockIdx.x, tid = threadIdx.x;
    if (bid < 6144) {
        int i = bid * 256 + tid;         // over 2048*768
        u16 h, l; splitbf(x[i], h, l);
        xh[i] = h; xl[i] = l;
        return;
    }
    if (bid < 6296) {
        int t = bid - 6144;              // 0..151
        int row = t >> 2;                // 0..37
        int h = (t & 3) * 256 + tid;     // 0..1023
        const int wb[8] = {1,2,3,4,5,5,6,7};
        if (row < 8) {
            int bk = wb[row];
            float acc = bs1[h];
            for (int j = 0; j < 25; ++j) acc = fmaf(wemb[bk*25+j], Ws1[(size_t)(1536+j)*HID + h], acc);
            wtabS[row*HID + h] = acc;
        } else if (row < 16) {
            int bk = wb[row-8];
            float acc = 0.f;
            for (int j = 0; j < 25; ++j) acc = fmaf(wemb[bk*25+j], Wp1[(size_t)(1536+j)*HID + h], acc);
            wtabPt[(row-8)*HID + h] = acc;
        } else if (row < 24) {
            int bk = wb[row-16];
            float acc = 0.f;
            for (int j = 0; j < 25; ++j) acc = fmaf(wemb[bk*25+j], Wp1[(size_t)(3097+j)*HID + h], acc);
            wtabPo[(row-16)*HID + h] = acc;
        } else {
            int tt = row - 24;           // 0..13
            float acc = bp1[h];
            for (int j = 0; j < 25; ++j) acc = fmaf(demb[tt*25+j], Wp1[(size_t)(3122+j)*HID + h], acc);
            dtab[tt*HID + h] = acc;
        }
        return;
    }
    // transpose jobs
    const int tb = bid - 6296;           // 0..6655
    const int tr = tid >> 3;             // 0..31
    const int tc4 = (tid & 7) * 4;       // 0,4,..,28
    int job, tk, tn, blk = 0;
    if (tb < 1536)      { job = 0; tk = tb % 24; tn = tb / 24; }
    else if (tb < 2560) { job = 1; int t = tb - 1536; tk = t & 31; tn = t >> 5; }
    else if (tb < 3584) { job = 2; int t = tb - 2560; tk = t & 31; tn = t >> 5; }
    else                { job = 3; int t = tb - 3584; blk = t / 768; int r = t - blk * 768; tk = r % 24; tn = r / 24; }
    const int k0 = tk * 32, n0 = tn * 32;

    int k = k0 + tr;
    float4 v;
    if (job == 0) {
        const float* s = (n0 < 1024) ? (Ws1 + (size_t)k * HID + n0)
                                     : (Ws1 + (size_t)(768 + k) * HID + (n0 - 1024));
        v = *(const float4*)(s + tc4);
    } else if (job == 1) {
        v = *(const float4*)(Ws2 + (size_t)k * HID + n0 + tc4);
    } else if (job == 2) {
        v = *(const float4*)(Wp2 + (size_t)k * HID + n0 + tc4);
    } else {
        const int roff[4] = {0, 768, 1561, 2329};   // (T,p0),(T,p1),(O,p0),(O,p1)
        v = *(const float4*)(Wp1 + (size_t)(roff[blk] + k) * HID + n0 + tc4);
    }
    tile[tr][tc4+0] = v.x; tile[tr][tc4+1] = v.y;
    tile[tr][tc4+2] = v.z; tile[tr][tc4+3] = v.w;
    __syncthreads();

    int nn = n0 + tr;
    float w0 = tile[tc4+0][tr], w1 = tile[tc4+1][tr];
    float w2 = tile[tc4+2][tr], w3 = tile[tc4+3][tr];
    if (job == 0) {
        size_t d = (size_t)nn * 768 + k0 + tc4;
        u16 h0,l0,h1,l1,h2,l2,h3,l3;
        splitbf(w0,h0,l0); splitbf(w1,h1,l1); splitbf(w2,h2,l2); splitbf(w3,h3,l3);
        *(uint2*)(W1Th + d) = make_uint2((u32)h0 | ((u32)h1 << 16), (u32)h2 | ((u32)h3 << 16));
        *(uint2*)(W1Tl + d) = make_uint2((u32)l0 | ((u32)l1 << 16), (u32)l2 | ((u32)l3 << 16));
    } else if (job == 1) {
        size_t d = (size_t)nn * 1024 + k0 + tc4;
        u16 h0,l0,h1,l1,h2,l2,h3,l3;
        splitbf(w0,h0,l0); splitbf(w1,h1,l1); splitbf(w2,h2,l2); splitbf(w3,h3,l3);
        *(uint2*)(W2Th + d) = make_uint2((u32)h0 | ((u32)h1 << 16), (u32)h2 | ((u32)h3 << 16));
        *(uint2*)(W2Tl + d) = make_uint2((u32)l0 | ((u32)l1 << 16), (u32)l2 | ((u32)l3 << 16));
    } else if (job == 2) {
        size_t d = (size_t)nn * 1024 + k0 + tc4;
        *(uint2*)(Wp2T + d) = make_uint2((u32)f2bf(w0) | ((u32)f2bf(w1) << 16),
                                         (u32)f2bf(w2) | ((u32)f2bf(w3) << 16));
    } else {
        size_t d = (size_t)blk * 786432 + (size_t)nn * 768 + k0 + tc4;
        *(uint2*)(Wp1T4 + d) = make_uint2((u32)f2bf(w0) | ((u32)f2bf(w1) << 16),
                                          (u32)f2bf(w2) | ((u32)f2bf(w3) << 16));
    }
}

// ---------------------------------------------------------------------------
// Error-compensated split-bf16 MFMA GEMM: C = AhBh + AlBh + AhBl  (XALL path)
// 128x128 tile, BK=32, global_load_lds staging, XCD-aware grid.
// ---------------------------------------------------------------------------
__global__ __launch_bounds__(256) void k_gemm3bf(
    const u16* __restrict__ Ah, const u16* __restrict__ Al, int lda,
    const u16* __restrict__ BTh, const u16* __restrict__ BTl, int ldb,
    float* __restrict__ C, int ldc,
    int M, int K, int nby, int sft)
{
    int bx, by;
    xcd_map(blockIdx.x, sft, bx, by);
    if (by >= nby) return;
    __shared__ __align__(16) u16 sm[4 * 128 * 32];     // 32 KiB
    u16* sAh = sm;
    u16* sAl = sm + 4096;
    u16* sBh = sm + 8192;
    u16* sBl = sm + 12288;
    const int tid = threadIdx.x;
    const int bm = by * 128, bn = bx * 128;
    const int wave = tid >> 6, lane = tid & 63;
    const int wr = wave >> 1, wc = wave & 1;
    const int q = lane >> 4, tl = lane & 15;

    f32x4 zero = {0.f, 0.f, 0.f, 0.f};
    f32x4 acc[4][4];
#pragma unroll
    for (int i = 0; i < 4; ++i)
#pragma unroll
        for (int j = 0; j < 4; ++j) acc[i][j] = zero;

    const int srow = lane >> 2;
    const int scol = (lane & 3) * 8;
    int ra0 = bm + wave * 32 + srow;      if (ra0 >= M) ra0 = M - 1;
    int ra1 = bm + wave * 32 + 16 + srow; if (ra1 >= M) ra1 = M - 1;
    const int rb0 = bn + wave * 32 + srow;
    const int rb1 = bn + wave * 32 + 16 + srow;
    u16* dA0 = sAh + wave * 1024;  u16* dA1 = dA0 + 512;
    u16* dL0 = sAl + wave * 1024;  u16* dL1 = dL0 + 512;
    u16* dB0 = sBh + wave * 1024;  u16* dB1 = dB0 + 512;
    u16* dC0 = sBl + wave * 1024;  u16* dC1 = dC0 + 512;
    const u16* gA0 = Ah  + (size_t)ra0 * lda + scol;
    const u16* gA1 = Ah  + (size_t)ra1 * lda + scol;
    const u16* gL0 = Al  + (size_t)ra0 * lda + scol;
    const u16* gL1 = Al  + (size_t)ra1 * lda + scol;
    const u16* gB0 = BTh + (size_t)rb0 * ldb + scol;
    const u16* gB1 = BTh + (size_t)rb1 * ldb + scol;
    const u16* gC0 = BTl + (size_t)rb0 * ldb + scol;
    const u16* gC1 = BTl + (size_t)rb1 * ldb + scol;

    for (int k0 = 0; k0 < K; k0 += 32) {
        gld_lds16(gA0 + k0, dA0);
        gld_lds16(gA1 + k0, dA1);
        gld_lds16(gL0 + k0, dL0);
        gld_lds16(gL1 + k0, dL1);
        gld_lds16(gB0 + k0, dB0);
        gld_lds16(gB1 + k0, dB1);
        gld_lds16(gC0 + k0, dC0);
        gld_lds16(gC1 + k0, dC1);
        __syncthreads();
        bf16x8 ah[4], al[4], bh[4], bl[4];
#pragma unroll
        for (int t = 0; t < 4; ++t) {
            int arow = (wr*64 + t*16 + tl) * 32 + q*8;
            int brow = (wc*64 + t*16 + tl) * 32 + q*8;
            ah[t] = *(const bf16x8*)(&sAh[arow]);
            al[t] = *(const bf16x8*)(&sAl[arow]);
            bh[t] = *(const bf16x8*)(&sBh[brow]);
            bl[t] = *(const bf16x8*)(&sBl[brow]);
        }
#pragma unroll
        for (int ti = 0; ti < 4; ++ti)
#pragma unroll
            for (int tj = 0; tj < 4; ++tj) {
                acc[ti][tj] = __builtin_amdgcn_mfma_f32_16x16x32_bf16(ah[ti], bh[tj], acc[ti][tj], 0, 0, 0);
                acc[ti][tj] = __builtin_amdgcn_mfma_f32_16x16x32_bf16(al[ti], bh[tj], acc[ti][tj], 0, 0, 0);
                acc[ti][tj] = __builtin_amdgcn_mfma_f32_16x16x32_bf16(ah[ti], bl[tj], acc[ti][tj], 0, 0, 0);
            }
        __syncthreads();
    }
    // C/D layout: col = lane&15, row = (lane>>4)*4 + reg  [measured m89/m91]
#pragma unroll
    for (int ti = 0; ti < 4; ++ti) {
#pragma unroll
        for (int tj = 0; tj < 4; ++tj) {
            int gcol = bn + wc*64 + tj*16 + tl;
#pragma unroll
            for (int r = 0; r < 4; ++r) {
                int grow = bm + wr*64 + ti*16 + q*4 + r;
                if (grow >= M) continue;
                C[(size_t)grow * ldc + gcol] = acc[ti][tj][r];
            }
        }
    }
}

// ---------------------------------------------------------------------------
// Span layer-2 GEMM with FUSED layer-3 projection epilogue (deterministic).
// ---------------------------------------------------------------------------
__global__ __launch_bounds__(256) void k_span_l2(
    const u16* __restrict__ Ah, const u16* __restrict__ Al,
    const u16* __restrict__ BTh, const u16* __restrict__ BTl,
    const float* __restrict__ bs2, const float* __restrict__ Ws3,
    float* __restrict__ part, int M)
{
    int bx, by;
    xcd_map(blockIdx.x, 3, bx, by);
    if (by >= 127) return;
    __shared__ __align__(16) u16 sm[4 * 128 * 32];
    u16* sAh = sm;
    u16* sAl = sm + 4096;
    u16* sBh = sm + 8192;
    u16* sBl = sm + 12288;
    const int tid = threadIdx.x;
    const int bm = by * 128, bn = bx * 128;
    const int wave = tid >> 6, lane = tid & 63;
    const int wr = wave >> 1, wc = wave & 1;
    const int q = lane >> 4, tl = lane & 15;

    f32x4 zero = {0.f, 0.f, 0.f, 0.f};
    f32x4 acc[4][4];
#pragma unroll
    for (int i = 0; i < 4; ++i)
#pragma unroll
        for (int j = 0; j < 4; ++j) acc[i][j] = zero;

    const int srow = lane >> 2;
    const int scol = (lane & 3) * 8;
    int ra0 = bm + wave * 32 + srow;      if (ra0 >= M) ra0 = M - 1;
    int ra1 = bm + wave * 32 + 16 + srow; if (ra1 >= M) ra1 = M - 1;
    const int rb0 = bn + wave * 32 + srow;
    const int rb1 = bn + wave * 32 + 16 + srow;
    u16* dA0 = sAh + wave * 1024;  u16* dA1 = dA0 + 512;
    u16* dL0 = sAl + wave * 1024;  u16* dL1 = dL0 + 512;
    u16* dB0 = sBh + wave * 1024;  u16* dB1 = dB0 + 512;
    u16* dC0 = sBl + wave * 1024;  u16* dC1 = dC0 + 512;
    const u16* gA0 = Ah  + (size_t)ra0 * HID + scol;
    const u16* gA1 = Ah  + (size_t)ra1 * HID + scol;
    const u16* gL0 = Al  + (size_t)ra0 * HID + scol;
    const u16* gL1 = Al  + (size_t)ra1 * HID + scol;
    const u16* gB0 = BTh + (size_t)rb0 * HID + scol;
    const u16* gB1 = BTh + (size_t)rb1 * HID + scol;
    const u16* gC0 = BTl + (size_t)rb0 * HID + scol;
    const u16* gC1 = BTl + (size_t)rb1 * HID + scol;

    for (int k0 = 0; k0 < HID; k0 += 32) {
        gld_lds16(gA0 + k0, dA0);
        gld_lds16(gA1 + k0, dA1);
        gld_lds16(gL0 + k0, dL0);
        gld_lds16(gL1 + k0, dL1);
        gld_lds16(gB0 + k0, dB0);
        gld_lds16(gB1 + k0, dB1);
        gld_lds16(gC0 + k0, dC0);
        gld_lds16(gC1 + k0, dC1);
        __syncthreads();
        bf16x8 ah[4], al[4], bh[4], bl[4];
#pragma unroll
        for (int t = 0; t < 4; ++t) {
            int arow = (wr*64 + t*16 + tl) * 32 + q*8;
            int brow = (wc*64 + t*16 + tl) * 32 + q*8;
            ah[t] = *(const bf16x8*)(&sAh[arow]);
            al[t] = *(const bf16x8*)(&sAl[arow]);
            bh[t] = *(const bf16x8*)(&sBh[brow]);
            bl[t] = *(const bf16x8*)(&sBl[brow]);
        }
#pragma unroll
        for (int ti = 0; ti < 4; ++ti)
#pragma unroll
            for (int tj = 0; tj < 4; ++tj) {
                acc[ti][tj] = __builtin_amdgcn_mfma_f32_16x16x32_bf16(ah[ti], bh[tj], acc[ti][tj], 0, 0, 0);
                acc[ti][tj] = __builtin_amdgcn_mfma_f32_16x16x32_bf16(al[ti], bh[tj], acc[ti][tj], 0, 0, 0);
                acc[ti][tj] = __builtin_amdgcn_mfma_f32_16x16x32_bf16(ah[ti], bl[tj], acc[ti][tj], 0, 0, 0);
            }
        __syncthreads();
    }
    // fused L3: per row, partial dot over this wave's 64-col window
    const int slot = bx * 2 + wc;   // 0..15
#pragma unroll
    for (int ti = 0; ti < 4; ++ti) {
#pragma unroll
        for (int r = 0; r < 4; ++r) {
            int grow = bm + wr*64 + ti*16 + q*4 + r;
            float l0 = 0.f, l1 = 0.f, l2 = 0.f;
#pragma unroll
            for (int tj = 0; tj < 4; ++tj) {
                int gcol = bn + wc*64 + tj*16 + tl;
                float v = fmaxf(acc[ti][tj][r] + bs2[gcol], 0.f);
                const float* w3 = Ws3 + gcol * 3;
                l0 = fmaf(v, w3[0], l0);
                l1 = fmaf(v, w3[1], l1);
                l2 = fmaf(v, w3[2], l2);
            }
#pragma unroll
            for (int off = 8; off > 0; off >>= 1) {
                l0 += __shfl_down(l0, off, 16);
                l1 += __shfl_down(l1, off, 16);
                l2 += __shfl_down(l2, off, 16);
            }
            if (tl == 0 && grow < M) {
                float* dst = part + ((size_t)grow * 16 + slot) * 3;
                dst[0] = l0; dst[1] = l1; dst[2] = l2;
            }
        }
    }
}

// ---------------------------------------------------------------------------
// Gathered pair layer-1, split-K over p: TO2[p][r] = xh[toks[r + p*1024]]@B(p)
// ---------------------------------------------------------------------------
__global__ __launch_bounds__(256) void k_pairL1(
    const u16* __restrict__ xh, const u16* __restrict__ Wp1T4,
    float* __restrict__ TO2, const int* __restrict__ toks)
{
    __shared__ __align__(16) u16 sm[2 * 64 * 32];   // A 4KB | B 4KB
    u16* sA = sm;
    u16* sB = sm + 2048;
    const int tid = threadIdx.x;
    const int bid = blockIdx.x;
    const int p = bid >> 8;                  // 0/1
    const int bx = bid & 15, by = (bid >> 4) & 15;
    const int bm = by * 64, bn = bx * 64;
    const int wave = tid >> 6, lane = tid & 63;
    const int wr = wave >> 1, wc = wave & 1;
    const int q = lane >> 4, tl = lane & 15;
    const bool isO = bm >= 512;

    f32x4 zero = {0.f, 0.f, 0.f, 0.f};
    f32x4 acc[2][2];
#pragma unroll
    for (int i = 0; i < 2; ++i)
#pragma unroll
        for (int j = 0; j < 2; ++j) acc[i][j] = zero;

    const int srow = tid >> 2;
    const int scol = (tid & 3) * 8;
    u16* dA = sA + wave * 512;
    u16* dB = sB + wave * 512;

    int arow = toks[bm + srow + p * 1024];    // per-lane row gather
    const u16* gA = xh + (size_t)arow * DIM + scol;
    const u16* gB = Wp1T4 + ((size_t)((isO ? 2 : 0) + p) * 1024 + bn + srow) * DIM + scol;
    for (int k0 = 0; k0 < DIM; k0 += 32) {
        gld_lds16(gA + k0, dA);
        gld_lds16(gB + k0, dB);
        __syncthreads();
        bf16x8 af[2], bf[2];
#pragma unroll
        for (int t = 0; t < 2; ++t) {
            af[t] = *(const bf16x8*)(&sA[(wr*32 + t*16 + tl) * 32 + q*8]);
            bf[t] = *(const bf16x8*)(&sB[(wc*32 + t*16 + tl) * 32 + q*8]);
        }
#pragma unroll
        for (int ti = 0; ti < 2; ++ti)
#pragma unroll
            for (int tj = 0; tj < 2; ++tj)
                acc[ti][tj] = __builtin_amdgcn_mfma_f32_16x16x32_bf16(af[ti], bf[tj], acc[ti][tj], 0, 0, 0);
        __syncthreads();
    }
    float* dstb = TO2 + (size_t)p * 1024 * HID;
#pragma unroll
    for (int ti = 0; ti < 2; ++ti) {
#pragma unroll
        for (int tj = 0; tj < 2; ++tj) {
            int gcol = bn + wc*32 + tj*16 + tl;
#pragma unroll
            for (int r = 0; r < 4; ++r) {
                int grow = bm + wr*32 + ti*16 + q*4 + r;
                dstb[(size_t)grow * HID + gcol] = acc[ti][tj][r];
            }
        }
    }
}

// h1s = relu(XALL[b,start,0:1024] + XALL[b,end-1,1024:2048] + wtabS[w-1]) -> split bf16
__global__ __launch_bounds__(256) void k_build_h1s(
    const float* __restrict__ XALL, const float* __restrict__ wtabS,
    u16* __restrict__ h1h, u16* __restrict__ h1l)
{
    int r = blockIdx.x;                 // 0..16159
    int b = r / NSPAN, s = r - b * NSPAN;
    int st, en, w; span_decode(s, st, en, w);
    const float4* xs = (const float4*)(XALL + (size_t)(b*SEQ + st) * 2048);
    const float4* xe = (const float4*)(XALL + (size_t)(b*SEQ + en - 1) * 2048 + 1024);
    const float4* wt = (const float4*)(wtabS + (size_t)(w-1) * HID);
    int t = threadIdx.x;
    float4 a = xs[t], bz = xe[t], c = wt[t];
    float v0 = fmaxf(a.x + bz.x + c.x, 0.f);
    float v1 = fmaxf(a.y + bz.y + c.y, 0.f);
    float v2 = fmaxf(a.z + bz.z + c.z, 0.f);
    float v3 = fmaxf(a.w + bz.w + c.w, 0.f);
    u16 h0,l0,h1,l1,h2,l2,h3,l3;
    splitbf(v0,h0,l0); splitbf(v1,h1,l1); splitbf(v2,h2,l2); splitbf(v3,h3,l3);
    size_t base = (size_t)r * HID + t * 4;
    *(uint2*)(h1h + base) = make_uint2((u32)h0 | ((u32)h1 << 16), (u32)h2 | ((u32)h3 << 16));
    *(uint2*)(h1l + base) = make_uint2((u32)l0 | ((u32)l1 << 16), (u32)l2 | ((u32)l3 << 16));
}

// ---------------------------------------------------------------------------
// k_topk (fused with span reduce+softmax): reduces partS (fixed order), writes
// out[], packs keys, bitonic-sorts 2048 u64 keys, emits top-64 + token maps.
// ---------------------------------------------------------------------------
__global__ __launch_bounds__(256) void k_topk(
    const float* __restrict__ partS, const float* __restrict__ bs3,
    float* __restrict__ out, int* __restrict__ t_idx, int* __restrict__ o_idx,
    int* __restrict__ toks)
{
    int b = blockIdx.x >> 1;
    int head = 1 + (blockIdx.x & 1);
    int* outp = (head == 1 ? t_idx : o_idx) + b * NZ;
    __shared__ u64 keys[2048];
    int tid = threadIdx.x;
#pragma unroll
    for (int ii = 0; ii < 8; ++ii) {
        int s = tid + ii * 256;          // 0..2047
        u32 fb = 0;
        if (s < NSPAN) {
            const float* p = partS + (size_t)(b * NSPAN + s) * 48;
            float s0 = bs3[0], s1 = bs3[1], s2 = bs3[2];
#pragma unroll
            for (int t = 0; t < 16; ++t) {
                s0 += p[t*3]; s1 += p[t*3+1]; s2 += p[t*3+2];
            }
            float m = fmaxf(s0, fmaxf(s1, s2));
            float e0 = expf(s0 - m), e1 = expf(s1 - m), e2 = expf(s2 - m);
            float inv = 1.f / (e0 + e1 + e2);
            float p0 = e0 * inv, p1 = e1 * inv, p2 = e2 * inv;
            float* o = out + (size_t)(b * NSPAN + s) * 3;
            o[0] = p0; o[1] = p1; o[2] = p2;
            union { float f; u32 u; } x;
            x.f = (head == 1) ? p1 : p2;
            fb = x.u;
        }
        keys[s] = ((u64)fb << 32) | (u64)(0xFFFFFFFFu - (u32)s);
    }
    __syncthreads();
    for (int k = 2; k <= 2048; k <<= 1) {
        for (int j = k >> 1; j > 0; j >>= 1) {
#pragma unroll
            for (int ii = 0; ii < 8; ++ii) {
                int i = tid + ii * 256;
                int ixj = i ^ j;
                if (ixj > i) {
                    u64 a = keys[i], c = keys[ixj];
                    bool desc = (i & k) == 0;
                    bool wrong = desc ? (a < c) : (a > c);
                    if (wrong) { keys[i] = c; keys[ixj] = a; }
                }
            }
            __syncthreads();
        }
    }
    if (tid < NZ) {
        u64 key = keys[tid];
        int fi = (int)(0xFFFFFFFFu - (u32)(key & 0xFFFFFFFFu));
        if (fi < 0 || fi >= NSPAN) fi = 0;   // paranoia
        outp[tid] = fi;
        int st, en, w; span_decode(fi, st, en, w);
        int base = (head == 1 ? 0 : 512) + b * NZ + tid;
        toks[base] = b * SEQ + st;
        toks[1024 + base] = b * SEQ + en - 1;
    }
}

// ---------------------------------------------------------------------------
// k_build_h1p v2 (LDS-tiled): one block per (b, 8 i's, 4 j's) -> 32 rows.
// T-rows (T0+T1+wtabPt) and O-rows (O0+O1+wtabPo) staged ONCE in LDS and
// reused across the tile -- cuts logical L2 reads ~3x vs per-row blocks.
// Sum re-association changes fp32 bits at ~1e-7 (pre-bf16-quantization noise).
// ---------------------------------------------------------------------------
__global__ __launch_bounds__(256) void k_build_h1p(
    const float* __restrict__ TO2, const int* __restrict__ t_idx, const int* __restrict__ o_idx,
    const float* __restrict__ wtabPt, const float* __restrict__ wtabPo,
    const float* __restrict__ dtab, u16* __restrict__ h1p)
{
    __shared__ float Ts[8][HID];    // 32 KB
    __shared__ float Os[4][HID];    // 16 KB
    const int bid = blockIdx.x;     // 1024 = 8 b x 8 it x 16 jt
    const int b = bid >> 7;
    const int it = (bid >> 4) & 7;
    const int jt = bid & 15;
    const int i0 = it * 8, j0 = jt * 4;
    const int tid = threadIdx.x;
    const int k4 = tid * 4;
    const size_t PS = (size_t)1024 * HID;

    int tinfo[8][2];                // (ta, tb) per i
    int oinfo[4][2];                // (oc, od) per j
#pragma unroll
    for (int r = 0; r < 8; ++r) {
        int i = i0 + r;
        int ts = t_idx[b*64 + i];
        int ta, tb, wt; span_decode(ts, ta, tb, wt);
        tinfo[r][0] = ta; tinfo[r][1] = tb;
        float4 t0 = *(const float4*)(TO2 + (size_t)(b*64 + i) * HID + k4);
        float4 t1 = *(const float4*)(TO2 + PS + (size_t)(b*64 + i) * HID + k4);
        float4 pp = *(const float4*)(wtabPt + (size_t)(wt-1) * HID + k4);
        Ts[r][k4+0] = t0.x + t1.x + pp.x;
        Ts[r][k4+1] = t0.y + t1.y + pp.y;
        Ts[r][k4+2] = t0.z + t1.z + pp.z;
        Ts[r][k4+3] = t0.w + t1.w + pp.w;
    }
#pragma unroll
    for (int r = 0; r < 4; ++r) {
        int j = j0 + r;
        int os = o_idx[b*64 + j];
        int oc, od, wo; span_decode(os, oc, od, wo);
        oinfo[r][0] = oc; oinfo[r][1] = od;
        float4 o0 = *(const float4*)(TO2 + (size_t)(512 + b*64 + j) * HID + k4);
        float4 o1 = *(const float4*)(TO2 + PS + (size_t)(512 + b*64 + j) * HID + k4);
        float4 qq = *(const float4*)(wtabPo + (size_t)(wo-1) * HID + k4);
        Os[r][k4+0] = o0.x + o1.x + qq.x;
        Os[r][k4+1] = o0.y + o1.y + qq.y;
        Os[r][k4+2] = o0.z + o1.z + qq.z;
        Os[r][k4+3] = o0.w + o1.w + qq.w;
    }
    __syncthreads();

#pragma unroll
    for (int ri = 0; ri < 8; ++ri) {
#pragma unroll
        for (int rj = 0; rj < 4; ++rj) {
            int ta = tinfo[ri][0], tb = tinfo[ri][1];
            int oc = oinfo[rj][0], od = oinfo[rj][1];
            int d1 = tb - oc; d1 = d1 < 0 ? -d1 : d1;
            int d2 = ta - od; d2 = d2 < 0 ? -d2 : d2;
            int dist = d1 < d2 ? d1 : d2;
            int db = dbucket(dist);
            const float4 dd = *(const float4*)(dtab + (size_t)db * HID + k4);
            float vx = fmaxf(Ts[ri][k4+0] + Os[rj][k4+0] + dd.x, 0.f);
            float vy = fmaxf(Ts[ri][k4+1] + Os[rj][k4+1] + dd.y, 0.f);
            float vz = fmaxf(Ts[ri][k4+2] + Os[rj][k4+2] + dd.z, 0.f);
            float vw = fmaxf(Ts[ri][k4+3] + Os[rj][k4+3] + dd.w, 0.f);
            u32 p0 = (u32)f2bf(vx) | ((u32)f2bf(vy) << 16);
            u32 p1 = (u32)f2bf(vz) | ((u32)f2bf(vw) << 16);
            int row = b * 4096 + (i0 + ri) * 64 + (j0 + rj);
            *(uint2*)(h1p + (size_t)row * HID + k4) = make_uint2(p0, p1);
        }
    }
}

// pair layer2 with FUSED layer-3 projection epilogue (BK=32, round-12 config).
__global__ __launch_bounds__(256) void k_pair_l2(
    const u16* __restrict__ Abf, const u16* __restrict__ BT,
    const float* __restrict__ bp2, const float* __restrict__ Wp3,
    float* __restrict__ part)
{
    int bx, by;
    xcd_map(blockIdx.x, 3, bx, by);
    __shared__ __align__(16) u16 sm[2 * 128 * 32];     // 16 KiB
    u16* As = sm;
    u16* Bs = sm + 4096;
    const int tid = threadIdx.x;
    const int bm = by * 128, bn = bx * 128;
    const int wave = tid >> 6, lane = tid & 63;
    const int wr = wave >> 1, wc = wave & 1;
    const int q = lane >> 4, tl = lane & 15;

    f32x4 zero = {0.f, 0.f, 0.f, 0.f};
    f32x4 acc[4][4];
#pragma unroll
    for (int i = 0; i < 4; ++i)
#pragma unroll
        for (int j = 0; j < 4; ++j) acc[i][j] = zero;

    const int srow = lane >> 2;
    const int scol = (lane & 3) * 8;
    const u16* gA0 = Abf + (size_t)(bm + wave*32 + srow) * 1024 + scol;
    const u16* gA1 = Abf + (size_t)(bm + wave*32 + 16 + srow) * 1024 + scol;
    const u16* gB0 = BT  + (size_t)(bn + wave*32 + srow) * 1024 + scol;
    const u16* gB1 = BT  + (size_t)(bn + wave*32 + 16 + srow) * 1024 + scol;
    u16* dA0 = As + wave * 1024;  u16* dA1 = dA0 + 512;
    u16* dB0 = Bs + wave * 1024;  u16* dB1 = dB0 + 512;

    for (int k0 = 0; k0 < 1024; k0 += 32) {
        gld_lds16(gA0 + k0, dA0);
        gld_lds16(gA1 + k0, dA1);
        gld_lds16(gB0 + k0, dB0);
        gld_lds16(gB1 + k0, dB1);
        __syncthreads();
        bf16x8 af[4], bf[4];
#pragma unroll
        for (int t = 0; t < 4; ++t) {
            af[t] = *(const bf16x8*)(&As[(wr*64 + t*16 + tl) * 32 + q*8]);
            bf[t] = *(const bf16x8*)(&Bs[(wc*64 + t*16 + tl) * 32 + q*8]);
        }
#pragma unroll
        for (int ti = 0; ti < 4; ++ti)
#pragma unroll
            for (int tj = 0; tj < 4; ++tj)
                acc[ti][tj] = __builtin_amdgcn_mfma_f32_16x16x32_bf16(af[ti], bf[tj], acc[ti][tj], 0, 0, 0);
        __syncthreads();
    }
    // fused L3 projection
    const int slot = bx * 2 + wc;   // 0..15
#pragma unroll
    for (int ti = 0; ti < 4; ++ti) {
#pragma unroll
        for (int r = 0; r < 4; ++r) {
            int grow = bm + wr*64 + ti*16 + q*4 + r;
            float l0 = 0.f, l1 = 0.f, l2 = 0.f, l3 = 0.f;
#pragma unroll
            for (int tj = 0; tj < 4; ++tj) {
                int gcol = bn + wc*64 + tj*16 + tl;
                float v = fmaxf(acc[ti][tj][r] + bp2[gcol], 0.f);
                const float4 w = *(const float4*)(Wp3 + gcol * 4);
                l0 = fmaf(v, w.x, l0); l1 = fmaf(v, w.y, l1);
                l2 = fmaf(v, w.z, l2); l3 = fmaf(v, w.w, l3);
            }
#pragma unroll
            for (int off = 8; off > 0; off >>= 1) {
                l0 += __shfl_down(l0, off, 16);
                l1 += __shfl_down(l1, off, 16);
                l2 += __shfl_down(l2, off, 16);
                l3 += __shfl_down(l3, off, 16);
            }
            if (tl == 0) {
                float* dst = part + ((size_t)grow * 16 + slot) * 4;
                dst[0] = l0; dst[1] = l1; dst[2] = l2; dst[3] = l3;
            }
        }
    }
}

// reduce 16 slots (fixed order) + softmax -> out[48480 + r*4 + c]
__global__ __launch_bounds__(256) void k_pair_red(
    const float* __restrict__ part, const float* __restrict__ bp3,
    float* __restrict__ out)
{
    int r = blockIdx.x * 256 + threadIdx.x;   // 32768 = 128*256 exact
    const float4* p = (const float4*)(part + (size_t)r * 64);
    float s0 = bp3[0], s1 = bp3[1], s2 = bp3[2], s3 = bp3[3];
#pragma unroll
    for (int t = 0; t < 16; ++t) {
        float4 v = p[t];
        s0 += v.x; s1 += v.y; s2 += v.z; s3 += v.w;
    }
    float m = fmaxf(fmaxf(s0, s1), fmaxf(s2, s3));
    float e0 = expf(s0 - m), e1 = expf(s1 - m), e2 = expf(s2 - m), e3 = expf(s3 - m);
    float inv = 1.f / (e0 + e1 + e2 + e3);
    float* o = out + (size_t)r * 4;
    o[0] = e0 * inv; o[1] = e1 * inv; o[2] = e2 * inv; o[3] = e3 * inv;
}

extern "C" void kernel_launch(void* const* d_in, const int* in_sizes, int n_in,
                              void* d_out, int out_size, void* d_ws, size_t ws_size,
                              hipStream_t stream)
{
    const float* x    = (const float*)d_in[0];
    const float* wemb = (const float*)d_in[1];
    const float* demb = (const float*)d_in[2];
    const float* Ws1  = (const float*)d_in[3];
    const float* bs1  = (const float*)d_in[4];
    const float* Ws2  = (const float*)d_in[5];
    const float* bs2  = (const float*)d_in[6];
    const float* Ws3  = (const float*)d_in[7];
    const float* bs3  = (const float*)d_in[8];
    const float* Wp1  = (const float*)d_in[9];
    const float* bp1  = (const float*)d_in[10];
    const float* Wp2  = (const float*)d_in[11];
    const float* bp2  = (const float*)d_in[12];
    const float* Wp3  = (const float*)d_in[13];
    const float* bp3  = (const float*)d_in[14];
    float* out = (float*)d_out;
    char* ws = (char*)d_ws;

    // ---- workspace arena, lifetime-aliased (~162 MB) ----
    const size_t RSZ = (size_t)32768 * HID * 2;   // 64 MiB
    size_t off = 0;
    auto alloc = [&](size_t bytes) -> void* {
        void* p = ws + off;
        off += (bytes + 255) & ~(size_t)255;
        return p;
    };
    char* R1 = (char*)alloc(RSZ);
    char* R2 = (char*)alloc(RSZ);
    u16*   h1h  = (u16*)R1;                              // 33.1 MB
    u16*   h1l  = (u16*)(R1 + (size_t)16160 * HID * 2);  // 33.1 MB
    float* XALL = (float*)R2;                            // 16 MiB
    u16*   xl   = (u16*)(R2 + (16u << 20));              // 3 MB
    u16*   W1Th = (u16*)(R2 + (19u << 20));              // 3 MB
    u16*   W1Tl = (u16*)(R2 + (22u << 20));              // 3 MB
    u16*   h1p  = (u16*)R2;                              // 64 MiB (after the above dead)
    u16*   xh     = (u16*)alloc((size_t)2048 * DIM * 2);     // 3 MB PERSISTENT
    float* TO2    = (float*)alloc((size_t)2 * 1024 * HID * 4);   // 8 MB
    float* partS  = (float*)alloc((size_t)16160 * 16 * 3 * 4);   // 3.1 MB
    float* partP  = (float*)alloc((size_t)32768 * 16 * 4 * 4);   // 8.4 MB
    u16*   W2Th   = (u16*)alloc((size_t)1024 * 1024 * 2);
    u16*   W2Tl   = (u16*)alloc((size_t)1024 * 1024 * 2);
    u16*   Wp2T   = (u16*)alloc((size_t)1024 * 1024 * 2);
    u16*   Wp1T4  = (u16*)alloc((size_t)4 * 1024 * 768 * 2);
    float* wtabS  = (float*)alloc(8 * HID * 4);
    float* wtabPt = (float*)alloc(8 * HID * 4);
    float* wtabPo = (float*)alloc(8 * HID * 4);
    float* dtab   = (float*)alloc(14 * HID * 4);
    int*   t_idx  = (int*)alloc(BATCH * NZ * 4);
    int*   o_idx  = (int*)alloc(BATCH * NZ * 4);
    int*   toks   = (int*)alloc(2048 * 4);
    (void)ws_size; (void)in_sizes; (void)n_in; (void)out_size;

    // prep (fused): x split + tables + all weight transposes
    k_prep<<<12952, 256, 0, stream>>>(x, xh, xl, wemb, demb, bs1, bp1,
                                      wtabS, wtabPt, wtabPo, dtab,
                                      Ws1, W1Th, W1Tl, Ws2, W2Th, W2Tl,
                                      Wp2, Wp2T, Wp1, Wp1T4);

    // layer-1 factorization: XALL = x2d @ [Ws1_top | Ws1_mid] (3-pass split-bf16)
    k_gemm3bf<<<256, 256, 0, stream>>>(xh, xl, 768, W1Th, W1Tl, 768,
                                       XALL, 2048, 2048, 768, 16, 4);
    k_build_h1s<<<16160, 256, 0, stream>>>(XALL, wtabS, h1h, h1l);
    // span layer2 + FUSED layer3 partials (3-pass split-bf16, deterministic)
    k_span_l2<<<1024, 256, 0, stream>>>(h1h, h1l, W2Th, W2Tl, bs2, Ws3, partS, 16160);
    // fused reduce+softmax+topk+toks
    k_topk<<<16, 256, 0, stream>>>(partS, bs3, out, t_idx, o_idx, toks);
    // gathered pair layer-1: split-K bf16 MFMA
    k_pairL1<<<512, 256, 0, stream>>>(xh, Wp1T4, TO2, toks);
    // h1p build: LDS-tiled (8i x 4j per block), 1024 blocks
    k_build_h1p<<<1024, 256, 0, stream>>>(TO2, t_idx, o_idx, wtabPt, wtabPo, dtab, h1p);
    // pair layer2 + FUSED layer3 partials (BK=32, best-known config)
    k_pair_l2<<<2048, 256, 0, stream>>>(h1p, Wp2T, bp2, Wp3, partP);
    k_pair_red<<<128, 256, 0, stream>>>(partP, bp3, out + 48480);
}